// Round 5
// baseline (244.598 us; speedup 1.0000x reference)
//
#include <hip/hip_runtime.h>
#include <hip/hip_bf16.h>

typedef __bf16 bf16_t;
typedef __bf16 bf16x8 __attribute__((ext_vector_type(8)));
typedef __bf16 bf16x4 __attribute__((ext_vector_type(4)));
typedef float  f32x4  __attribute__((ext_vector_type(4)));
typedef float  f32x2  __attribute__((ext_vector_type(2)));
typedef float  f32x16 __attribute__((ext_vector_type(16)));

#define B_ 8
#define C_ 256
#define L_ 4096
#define M_ 2048

__device__ __forceinline__ const bf16x8* ldg8(const bf16_t* p) {
    return reinterpret_cast<const bf16x8*>(p);
}

typedef __attribute__((address_space(3))) void as3_void;
typedef __attribute__((address_space(1))) const void as1_cvoid;

__device__ __forceinline__ void gload_lds16(const void* g, void* l) {
    __builtin_amdgcn_global_load_lds((as1_cvoid*)g, (as3_void*)l, 16, 0, 0);
}

__device__ __forceinline__ unsigned packbf(float a, float b) {
    unsigned short ua = __builtin_bit_cast(unsigned short, (bf16_t)a);
    unsigned short ub = __builtin_bit_cast(unsigned short, (bf16_t)b);
    return (unsigned)ua | ((unsigned)ub << 16);
}

// ---------------- kernel 1: weight conversion f32 -> bf16 ----------------
__global__ __launch_bounds__(256) void conv_w_kernel(
    const float* __restrict__ Wq, const float* __restrict__ Wk, const float* __restrict__ Wv,
    bf16_t* __restrict__ Wqb, bf16_t* __restrict__ Wkb, bf16_t* __restrict__ Wvb) {
    int idx = blockIdx.x * 256 + threadIdx.x;      // 0..196607
    int which = idx >> 16;
    int off = idx & 65535;
    const float* src = (which == 0) ? Wq : ((which == 1) ? Wk : Wv);
    bf16_t* dst = (which == 0) ? Wqb : ((which == 1) ? Wkb : Wvb);
    dst[off] = (bf16_t)src[off];
}

// ---------------- kernel 2: x -> xbt [B,L,C] bf16 ; xh -> xhbt [B,M,C] bf16 ----------------
__global__ __launch_bounds__(256) void prep_x_kernel(
    const float* __restrict__ x, bf16_t* __restrict__ xbt, bf16_t* __restrict__ xhbt) {
    __shared__ float tile[64][65];   // [c][l]
    const float INV_SQRT2 = 0.70710678118654752440f;
    int b = blockIdx.z, c0 = blockIdx.y * 64, l0 = blockIdx.x * 64;
    int t = threadIdx.x;
    int tr = t >> 6;      // 0..3
    int tc = t & 63;
    const float* xp = x + ((size_t)(b * C_ + c0) * L_) + l0;
#pragma unroll
    for (int i = 0; i < 16; ++i) {
        int row = i * 4 + tr;
        tile[row][tc] = xp[(size_t)row * L_ + tc];
    }
    __syncthreads();
    bf16_t* xo = xbt + ((size_t)(b * L_ + l0) * C_) + c0;
#pragma unroll
    for (int i = 0; i < 16; ++i) {
        int lr = i * 4 + tr;
        xo[(size_t)lr * C_ + tc] = (bf16_t)tile[tc][lr];
    }
    int m0 = l0 >> 1;
    bf16_t* xho = xhbt + ((size_t)(b * M_ + m0) * C_) + c0;
#pragma unroll
    for (int i = 0; i < 8; ++i) {
        int mr = i * 4 + tr;
        float v = (tile[tc][2 * mr] - tile[tc][2 * mr + 1]) * INV_SQRT2;
        xho[(size_t)mr * C_ + tc] = (bf16_t)v;
    }
}

// ---------------- kernel 3: out[b][n][o] = sum_c A[b][n][c] * W[o][c] + bias[o] ----------------
__global__ __launch_bounds__(256) void proj_nk_kernel(
    const bf16_t* __restrict__ A, const bf16_t* __restrict__ W,
    const float* __restrict__ bias, bf16_t* __restrict__ out, int N) {
    int b = blockIdx.y;
    int wave = threadIdx.x >> 6, lane = threadIdx.x & 63;
    int l15 = lane & 15, g = lane >> 4;
    int n0 = blockIdx.x * 64 + wave * 16;

    const bf16_t* Ap = A + ((size_t)(b * N + n0 + l15) * C_) + g * 8;
    bf16x8 af[8];
#pragma unroll
    for (int k = 0; k < 8; ++k) af[k] = *ldg8(Ap + k * 32);

    f32x4 acc[16];
#pragma unroll
    for (int ot = 0; ot < 16; ++ot) {
        float bb = bias[ot * 16 + l15];
        acc[ot][0] = bb; acc[ot][1] = bb; acc[ot][2] = bb; acc[ot][3] = bb;
    }
#pragma unroll
    for (int ot = 0; ot < 16; ++ot) {
        const bf16_t* Wp = W + ((size_t)(ot * 16 + l15) * C_) + g * 8;
#pragma unroll
        for (int k = 0; k < 8; ++k) {
            bf16x8 bfr = *ldg8(Wp + k * 32);
            acc[ot] = __builtin_amdgcn_mfma_f32_16x16x32_bf16(af[k], bfr, acc[ot], 0, 0, 0);
        }
    }
    bf16_t* op = out + ((size_t)(b * N + n0 + g * 4) * C_);
#pragma unroll
    for (int ot = 0; ot < 16; ++ot)
#pragma unroll
        for (int r = 0; r < 4; ++r)
            op[(size_t)r * C_ + ot * 16 + l15] = (bf16_t)acc[ot][r];
}

// ---------------- kernel 4: v'[b][o][m] = sum_c Wv[o][c] * xhbt[b][m][c] + bv[o] ----------------
__global__ __launch_bounds__(256) void proj_v_kernel(
    const bf16_t* __restrict__ xhbt, const bf16_t* __restrict__ W,
    const float* __restrict__ bias, bf16_t* __restrict__ out) {
    int b = blockIdx.z;
    int wave = threadIdx.x >> 6, lane = threadIdx.x & 63;
    int l15 = lane & 15, g = lane >> 4;
    int o0 = blockIdx.y * 64 + wave * 16;
    int m0 = blockIdx.x * 256;

    const bf16_t* Wp = W + ((size_t)(o0 + l15) * C_) + g * 8;
    bf16x8 af[8];
#pragma unroll
    for (int k = 0; k < 8; ++k) af[k] = *ldg8(Wp + k * 32);

    float bv4[4];
#pragma unroll
    for (int r = 0; r < 4; ++r) bv4[r] = bias[o0 + g * 4 + r];

    f32x4 acc[16];
#pragma unroll
    for (int mt = 0; mt < 16; ++mt) {
        acc[mt][0] = bv4[0]; acc[mt][1] = bv4[1]; acc[mt][2] = bv4[2]; acc[mt][3] = bv4[3];
    }
#pragma unroll
    for (int mt = 0; mt < 16; ++mt) {
        const bf16_t* Bp = xhbt + ((size_t)(b * M_ + m0 + mt * 16 + l15) * C_) + g * 8;
#pragma unroll
        for (int k = 0; k < 8; ++k) {
            bf16x8 bfr = *ldg8(Bp + k * 32);
            acc[mt] = __builtin_amdgcn_mfma_f32_16x16x32_bf16(af[k], bfr, acc[mt], 0, 0, 0);
        }
    }
    bf16_t* op = out + ((size_t)(b * C_ + o0 + g * 4) * M_) + m0;
#pragma unroll
    for (int mt = 0; mt < 16; ++mt)
#pragma unroll
        for (int r = 0; r < 4; ++r)
            op[(size_t)r * M_ + mt * 16 + l15] = (bf16_t)acc[mt][r];
}

// ---------------- kernel 5: flash attention, 32x32 MFMA, in-register P, 8-wave m-split ----------------
// 512 threads = 8 waves = 4 query-groups (qg) x 2 key-halves (mh).
// Wave (qg,mh): queries lt*128+qg*32..+32, keys m = mh*32..+32 of each KT=64 tile.
// Separate online-softmax state per wave; split-K merge via LDS at the end.
// __launch_bounds__(512,1): one 512-thr block/CU = 2 waves/SIMD; VGPR cap 256 (no spill).
#define KT 64
#define NT (M_ / KT)   // 32

__global__ __launch_bounds__(512, 1) void attn_kernel(
    const bf16_t* __restrict__ qb, const bf16_t* __restrict__ kb, const bf16_t* __restrict__ vb,
    const float* __restrict__ x, const float* __restrict__ gate, float* __restrict__ out) {
    // LDS: K 2x32KB | V 2x32KB = 128KB (reused as merge buffer) ; ml buffer 4KB
    __shared__ __align__(16) char smem[135168];
    char* Kbase_l = smem;
    char* Vbase_l = smem + 65536;

    const int t = threadIdx.x;
    const int wave = t >> 6, lane = t & 63;
    const int qg = wave & 3, mh = wave >> 2;
    const int l31 = lane & 31, hi = lane >> 5;
    const int bid = blockIdx.x;
    const int b = bid & 7;          // batch -> XCD affinity
    const int lt = bid >> 3;        // 0..31
    const int l0w = lt * 128 + qg * 32;

    // ---- staging geometry (global source pre-swizzled, LDS dest linear) ----
    const char* Kg = (const char*)(kb + (size_t)b * M_ * C_);
    const char* Vg = (const char*)(vb + (size_t)b * C_ * M_);
    int ksrc[4], vsrc[4];
#pragma unroll
    for (int i = 0; i < 4; ++i) {
        int chunk = i * 8 + wave;                 // 0..31 (1KB LDS chunks)
        int mr = chunk * 2 + (lane >> 5);         // K row 0..63
        ksrc[i] = mr * 512 + (((lane & 31) * 16) ^ ((mr & 7) << 4));
        int c = chunk * 8 + (lane >> 3);          // V row 0..255
        vsrc[i] = c * (M_ * 2) + (((lane & 7) * 16) ^ ((c & 7) << 4));
    }

    // ---- prologue: stage tile 0 into buffer 0 ----
#pragma unroll
    for (int i = 0; i < 4; ++i)
        gload_lds16(Kg + ksrc[i], Kbase_l + (i * 8 + wave) * 1024);
#pragma unroll
    for (int i = 0; i < 4; ++i)
        gload_lds16(Vg + vsrc[i], Vbase_l + (i * 8 + wave) * 1024);

    // ---- Q fragments in registers: qf[ks] = Q[l0w + l31][ks*16 + hi*8 .. +8] ----
    bf16x8 qf[16];
    const bf16_t* Qp = qb + ((size_t)(b * L_ + l0w + l31) * C_) + hi * 8;
#pragma unroll
    for (int ks = 0; ks < 16; ++ks) qf[ks] = *ldg8(Qp + ks * 16);

    f32x16 acc[8];
#pragma unroll
    for (int cb = 0; cb < 8; ++cb)
#pragma unroll
        for (int r = 0; r < 16; ++r) acc[cb][r] = 0.f;
    float m_run = -INFINITY, l_run = 0.f;

    asm volatile("s_waitcnt vmcnt(0)" ::: "memory");
    __builtin_amdgcn_s_barrier();
    asm volatile("" ::: "memory");

    for (int kt = 0; kt < NT; ++kt) {
        const int cur = kt & 1;
        // ---- issue DMA for tile kt+1 into other buffers ----
        if (kt + 1 < NT) {
            const char* Kn = Kg + (size_t)(kt + 1) * 32768;
            char* Kd = Kbase_l + (cur ^ 1) * 32768;
#pragma unroll
            for (int i = 0; i < 4; ++i)
                gload_lds16(Kn + ksrc[i], Kd + (i * 8 + wave) * 1024);
            const char* Vn = Vg + (size_t)(kt + 1) * 128;   // m-offset in bytes
            char* Vd = Vbase_l + (cur ^ 1) * 32768;
#pragma unroll
            for (int i = 0; i < 4; ++i)
                gload_lds16(Vn + vsrc[i], Vd + (i * 8 + wave) * 1024);
        }

        // ---- S = K' x Q : D[m,l] for this wave's m-half (rows mh*32 + 0..31) ----
        const char* Kc = Kbase_l + cur * 32768;
        const int mrow = mh * 32 + l31;
        const int msw = (mrow & 7) << 4;
        const int moff = mrow * 512;
        f32x16 s;
#pragma unroll
        for (int r = 0; r < 16; ++r) s[r] = 0.f;
        __builtin_amdgcn_s_setprio(1);
#pragma unroll
        for (int ks = 0; ks < 16; ++ks) {
            int cb2 = ks * 32 + hi * 16;
            bf16x8 a = *reinterpret_cast<const bf16x8*>(Kc + moff + (cb2 ^ msw));
            s = __builtin_amdgcn_mfma_f32_32x32x16_bf16(a, qf[ks], s, 0, 0, 0);
        }
        __builtin_amdgcn_s_setprio(0);

        // ---- online softmax over this m-half; lanes l and l+32 share query l ----
        float pv[16];
        float tm = -INFINITY;
#pragma unroll
        for (int r = 0; r < 16; ++r) {
            float v0 = s[r] * 0.0625f;
            pv[r] = v0;
            tm = fmaxf(tm, v0);
        }
        tm = fmaxf(tm, __shfl_xor(tm, 32));
        if (!__all(tm - m_run <= 8.0f)) {           // defer-max (T13)
            float m_new = fmaxf(m_run, tm);
            float corr = __expf(m_run - m_new);
#pragma unroll
            for (int cb = 0; cb < 8; ++cb)
#pragma unroll
                for (int r = 0; r < 16; ++r) acc[cb][r] *= corr;
            l_run *= corr;
            m_run = m_new;
        }
        float rs = 0.f;
#pragma unroll
        for (int i = 0; i < 16; ++i) { pv[i] = __expf(pv[i] - m_run); rs += pv[i]; }
        l_run += rs + __shfl_xor(rs, 32);

        // ---- build P B-frags in registers (k = m_local 0..31) ----
        union PW { unsigned u[4]; bf16x8 v; };
        bf16x8 pfrag[2];
        {
            unsigned Ce0 = packbf(pv[0], pv[1]);
            unsigned Ce1 = packbf(pv[2], pv[3]);
            unsigned Ce2 = packbf(pv[4], pv[5]);
            unsigned Ce3 = packbf(pv[6], pv[7]);
            unsigned Co0 = packbf(pv[8], pv[9]);
            unsigned Co1 = packbf(pv[10], pv[11]);
            unsigned Co2 = packbf(pv[12], pv[13]);
            unsigned Co3 = packbf(pv[14], pv[15]);
            unsigned Xe0 = (unsigned)__shfl_xor((int)Ce0, 32);
            unsigned Xe1 = (unsigned)__shfl_xor((int)Ce1, 32);
            unsigned Xe2 = (unsigned)__shfl_xor((int)Ce2, 32);
            unsigned Xe3 = (unsigned)__shfl_xor((int)Ce3, 32);
            unsigned Xo0 = (unsigned)__shfl_xor((int)Co0, 32);
            unsigned Xo1 = (unsigned)__shfl_xor((int)Co1, 32);
            unsigned Xo2 = (unsigned)__shfl_xor((int)Co2, 32);
            unsigned Xo3 = (unsigned)__shfl_xor((int)Co3, 32);
            PW we, wo;
            we.u[0] = hi ? Xe2 : Ce0;
            we.u[1] = hi ? Xe3 : Ce1;
            we.u[2] = hi ? Ce2 : Xe0;
            we.u[3] = hi ? Ce3 : Xe1;
            wo.u[0] = hi ? Xo2 : Co0;
            wo.u[1] = hi ? Xo3 : Co1;
            wo.u[2] = hi ? Co2 : Xo0;
            wo.u[3] = hi ? Co3 : Xo1;
            pfrag[0] = we.v;
            pfrag[1] = wo.v;
        }

        // ---- PV: D[c,l] += V[c,m] * P[m,l] over this wave's m-half ----
        const char* Vc = Vbase_l + cur * 32768;
        __builtin_amdgcn_s_setprio(1);
#pragma unroll
        for (int ks2 = 0; ks2 < 2; ++ks2) {
            int cb2 = (mh * 2 + ks2) * 32 + hi * 16;
#pragma unroll
            for (int cb = 0; cb < 8; ++cb) {
                int c = cb * 32 + l31;
                bf16x8 a = *reinterpret_cast<const bf16x8*>(Vc + c * 128 + (cb2 ^ ((c & 7) << 4)));
                acc[cb] = __builtin_amdgcn_mfma_f32_32x32x16_bf16(a, pfrag[ks2], acc[cb], 0, 0, 0);
            }
        }
        __builtin_amdgcn_s_setprio(0);

        // ---- publish: my DMAs landed; all waves done before buffer swap ----
        asm volatile("s_waitcnt vmcnt(0)" ::: "memory");
        __builtin_amdgcn_s_barrier();
        asm volatile("" ::: "memory");
    }

    // ---- split-K merge between wave pairs (qg, 0) <-> (qg, 1) ----
    f32x2* mlb = (f32x2*)(smem + 131072);
    f32x2 myml; myml[0] = m_run; myml[1] = l_run;
    mlb[wave * 64 + lane] = myml;
    __syncthreads();
    f32x2 pml = mlb[(wave ^ 4) * 64 + lane];
    float m_star = fmaxf(m_run, pml[0]);
    float f_self = __expf(m_run - m_star);
    float f_peer = __expf(pml[0] - m_star);
    float l_tot = l_run * f_self + pml[1] * f_peer;
#pragma unroll
    for (int cb = 0; cb < 8; ++cb)
#pragma unroll
        for (int r = 0; r < 16; ++r) acc[cb][r] *= f_self;

    // write export half (channels of the OTHER mh) to LDS
    char* xbuf = smem;
    const int myoff = (qg * 2 + mh) * 16384;
    const int e0 = (1 - mh) * 4;
    __syncthreads();   // ensure everyone read mlb & K/V reads long done before overwrite
#pragma unroll
    for (int cbl = 0; cbl < 4; ++cbl)
#pragma unroll
        for (int q = 0; q < 4; ++q) {
            f32x4 chunk;
#pragma unroll
            for (int j = 0; j < 4; ++j) chunk[j] = acc[e0 + cbl][q * 4 + j];
            *reinterpret_cast<f32x4*>(xbuf + myoff + (cbl * 4 + q) * 1024 + lane * 16) = chunk;
        }
    __syncthreads();

    // read partner's export (= my kept channels), finalize, epilogue
    const int poff = (qg * 2 + (1 - mh)) * 16384;
    float gt = tanhf(gate[0]);
    float scale = gt / l_tot;
    const float* xp = x + (size_t)b * C_ * L_;
    float* op = out + (size_t)b * C_ * L_;
    int lcol = l0w + l31;
    const int k0 = mh * 4;
#pragma unroll
    for (int cbl = 0; cbl < 4; ++cbl) {
        int cb = k0 + cbl;
#pragma unroll
        for (int q = 0; q < 4; ++q) {
            f32x4 pc = *reinterpret_cast<const f32x4*>(xbuf + poff + (cbl * 4 + q) * 1024 + lane * 16);
#pragma unroll
            for (int j = 0; j < 4; ++j) {
                int c = cb * 32 + j + 8 * q + 4 * hi;
                size_t idx = (size_t)c * L_ + lcol;
                op[idx] = (acc[cb][q * 4 + j] + pc[j]) * scale + xp[idx];
            }
        }
    }
}

extern "C" void kernel_launch(void* const* d_in, const int* in_sizes, int n_in,
                              void* d_out, int out_size, void* d_ws, size_t ws_size,
                              hipStream_t stream) {
    const float* x    = (const float*)d_in[0];
    const float* Wq   = (const float*)d_in[1];
    const float* bq   = (const float*)d_in[2];
    const float* Wk   = (const float*)d_in[3];
    const float* bk   = (const float*)d_in[4];
    const float* Wv   = (const float*)d_in[5];
    const float* bv   = (const float*)d_in[6];
    const float* gate = (const float*)d_in[7];
    float* out = (float*)d_out;

    char* ws = (char*)d_ws;
    const size_t szW   = (size_t)C_ * C_ * 2;          // 131072
    const size_t szXbt = (size_t)B_ * L_ * C_ * 2;     // 16777216
    const size_t szXh  = (size_t)B_ * M_ * C_ * 2;     // 8388608
    bf16_t* Wqb  = (bf16_t*)(ws);
    bf16_t* Wkb  = (bf16_t*)(ws + szW);
    bf16_t* Wvb  = (bf16_t*)(ws + 2 * szW);
    bf16_t* xbt  = (bf16_t*)(ws + 3 * szW);
    bf16_t* xhbt = (bf16_t*)(ws + 3 * szW + szXbt);
    bf16_t* qb   = (bf16_t*)(ws + 3 * szW + szXbt + szXh);
    bf16_t* kb   = (bf16_t*)(ws + 3 * szW + 2 * szXbt + szXh);
    bf16_t* vb   = (bf16_t*)(ws + 3 * szW + 2 * szXbt + 2 * szXh);

    conv_w_kernel<<<768, 256, 0, stream>>>(Wq, Wk, Wv, Wqb, Wkb, Wvb);
    prep_x_kernel<<<dim3(L_ / 64, C_ / 64, B_), 256, 0, stream>>>(x, xbt, xhbt);
    proj_nk_kernel<<<dim3(L_ / 64, B_), 256, 0, stream>>>(xbt, Wqb, bq, qb, L_);
    proj_nk_kernel<<<dim3(M_ / 64, B_), 256, 0, stream>>>(xhbt, Wkb, bk, kb, M_);
    proj_v_kernel<<<dim3(M_ / 256, C_ / 64, B_), 256, 0, stream>>>(xhbt, Wvb, bv, vb);
    attn_kernel<<<256, 512, 0, stream>>>(qb, kb, vb, x, gate, out);
}

// Round 6
// 199.139 us; speedup vs baseline: 1.2283x; 1.2283x over previous
//
#include <hip/hip_runtime.h>
#include <hip/hip_bf16.h>

typedef __bf16 bf16_t;
typedef __bf16 bf16x8 __attribute__((ext_vector_type(8)));
typedef __bf16 bf16x4 __attribute__((ext_vector_type(4)));
typedef float  f32x4  __attribute__((ext_vector_type(4)));
typedef float  f32x2  __attribute__((ext_vector_type(2)));
typedef float  f32x16 __attribute__((ext_vector_type(16)));

#define B_ 8
#define C_ 256
#define L_ 4096
#define M_ 2048

__device__ __forceinline__ const bf16x8* ldg8(const bf16_t* p) {
    return reinterpret_cast<const bf16x8*>(p);
}

typedef __attribute__((address_space(3))) void as3_void;
typedef __attribute__((address_space(1))) const void as1_cvoid;

__device__ __forceinline__ void gload_lds16(const void* g, void* l) {
    __builtin_amdgcn_global_load_lds((as1_cvoid*)g, (as3_void*)l, 16, 0, 0);
}

__device__ __forceinline__ unsigned packbf(float a, float b) {
    unsigned short ua = __builtin_bit_cast(unsigned short, (bf16_t)a);
    unsigned short ub = __builtin_bit_cast(unsigned short, (bf16_t)b);
    return (unsigned)ua | ((unsigned)ub << 16);
}

// ---------------- kernel 1: weight conversion f32 -> bf16 ----------------
__global__ __launch_bounds__(256) void conv_w_kernel(
    const float* __restrict__ Wq, const float* __restrict__ Wk, const float* __restrict__ Wv,
    bf16_t* __restrict__ Wqb, bf16_t* __restrict__ Wkb, bf16_t* __restrict__ Wvb) {
    int idx = blockIdx.x * 256 + threadIdx.x;      // 0..196607
    int which = idx >> 16;
    int off = idx & 65535;
    const float* src = (which == 0) ? Wq : ((which == 1) ? Wk : Wv);
    bf16_t* dst = (which == 0) ? Wqb : ((which == 1) ? Wkb : Wvb);
    dst[off] = (bf16_t)src[off];
}

// ---------------- kernel 2: x -> xbt [B,L,C] bf16 ; xh -> xhbt [B,M,C] bf16 ----------------
__global__ __launch_bounds__(256) void prep_x_kernel(
    const float* __restrict__ x, bf16_t* __restrict__ xbt, bf16_t* __restrict__ xhbt) {
    __shared__ float tile[64][65];   // [c][l]
    const float INV_SQRT2 = 0.70710678118654752440f;
    int b = blockIdx.z, c0 = blockIdx.y * 64, l0 = blockIdx.x * 64;
    int t = threadIdx.x;
    int tr = t >> 6;      // 0..3
    int tc = t & 63;
    const float* xp = x + ((size_t)(b * C_ + c0) * L_) + l0;
#pragma unroll
    for (int i = 0; i < 16; ++i) {
        int row = i * 4 + tr;
        tile[row][tc] = xp[(size_t)row * L_ + tc];
    }
    __syncthreads();
    bf16_t* xo = xbt + ((size_t)(b * L_ + l0) * C_) + c0;
#pragma unroll
    for (int i = 0; i < 16; ++i) {
        int lr = i * 4 + tr;
        xo[(size_t)lr * C_ + tc] = (bf16_t)tile[tc][lr];
    }
    int m0 = l0 >> 1;
    bf16_t* xho = xhbt + ((size_t)(b * M_ + m0) * C_) + c0;
#pragma unroll
    for (int i = 0; i < 8; ++i) {
        int mr = i * 4 + tr;
        float v = (tile[tc][2 * mr] - tile[tc][2 * mr + 1]) * INV_SQRT2;
        xho[(size_t)mr * C_ + tc] = (bf16_t)v;
    }
}

// ---------------- kernel 3: out[b][n][o] = sum_c A[b][n][c] * W[o][c] + bias[o] ----------------
__global__ __launch_bounds__(256) void proj_nk_kernel(
    const bf16_t* __restrict__ A, const bf16_t* __restrict__ W,
    const float* __restrict__ bias, bf16_t* __restrict__ out, int N) {
    int b = blockIdx.y;
    int wave = threadIdx.x >> 6, lane = threadIdx.x & 63;
    int l15 = lane & 15, g = lane >> 4;
    int n0 = blockIdx.x * 64 + wave * 16;

    const bf16_t* Ap = A + ((size_t)(b * N + n0 + l15) * C_) + g * 8;
    bf16x8 af[8];
#pragma unroll
    for (int k = 0; k < 8; ++k) af[k] = *ldg8(Ap + k * 32);

    f32x4 acc[16];
#pragma unroll
    for (int ot = 0; ot < 16; ++ot) {
        float bb = bias[ot * 16 + l15];
        acc[ot][0] = bb; acc[ot][1] = bb; acc[ot][2] = bb; acc[ot][3] = bb;
    }
#pragma unroll
    for (int ot = 0; ot < 16; ++ot) {
        const bf16_t* Wp = W + ((size_t)(ot * 16 + l15) * C_) + g * 8;
#pragma unroll
        for (int k = 0; k < 8; ++k) {
            bf16x8 bfr = *ldg8(Wp + k * 32);
            acc[ot] = __builtin_amdgcn_mfma_f32_16x16x32_bf16(af[k], bfr, acc[ot], 0, 0, 0);
        }
    }
    bf16_t* op = out + ((size_t)(b * N + n0 + g * 4) * C_);
#pragma unroll
    for (int ot = 0; ot < 16; ++ot)
#pragma unroll
        for (int r = 0; r < 4; ++r)
            op[(size_t)r * C_ + ot * 16 + l15] = (bf16_t)acc[ot][r];
}

// ---------------- kernel 4: v'[b][o][m] = sum_c Wv[o][c] * xhbt[b][m][c] + bv[o] ----------------
__global__ __launch_bounds__(256) void proj_v_kernel(
    const bf16_t* __restrict__ xhbt, const bf16_t* __restrict__ W,
    const float* __restrict__ bias, bf16_t* __restrict__ out) {
    int b = blockIdx.z;
    int wave = threadIdx.x >> 6, lane = threadIdx.x & 63;
    int l15 = lane & 15, g = lane >> 4;
    int o0 = blockIdx.y * 64 + wave * 16;
    int m0 = blockIdx.x * 256;

    const bf16_t* Wp = W + ((size_t)(o0 + l15) * C_) + g * 8;
    bf16x8 af[8];
#pragma unroll
    for (int k = 0; k < 8; ++k) af[k] = *ldg8(Wp + k * 32);

    float bv4[4];
#pragma unroll
    for (int r = 0; r < 4; ++r) bv4[r] = bias[o0 + g * 4 + r];

    f32x4 acc[16];
#pragma unroll
    for (int mt = 0; mt < 16; ++mt) {
        acc[mt][0] = bv4[0]; acc[mt][1] = bv4[1]; acc[mt][2] = bv4[2]; acc[mt][3] = bv4[3];
    }
#pragma unroll
    for (int mt = 0; mt < 16; ++mt) {
        const bf16_t* Bp = xhbt + ((size_t)(b * M_ + m0 + mt * 16 + l15) * C_) + g * 8;
#pragma unroll
        for (int k = 0; k < 8; ++k) {
            bf16x8 bfr = *ldg8(Bp + k * 32);
            acc[mt] = __builtin_amdgcn_mfma_f32_16x16x32_bf16(af[k], bfr, acc[mt], 0, 0, 0);
        }
    }
    bf16_t* op = out + ((size_t)(b * C_ + o0 + g * 4) * M_) + m0;
#pragma unroll
    for (int mt = 0; mt < 16; ++mt)
#pragma unroll
        for (int r = 0; r < 4; ++r)
            op[(size_t)r * M_ + mt * 16 + l15] = (bf16_t)acc[mt][r];
}

// ---------------- kernel 5: flash attention, 32x32 MFMA, in-register P, 8-wave m-split ----------------
// 512 threads = 8 waves = 4 query-groups (qg) x 2 key-halves (mh).
// Wave (qg,mh): queries lt*128+qg*32..+32, keys m = mh*32..+32 of each KT=64 tile.
// Separate online-softmax state per wave; split-K merge via LDS at the end.
// NOTE: every acc[] index must be COMPILE-TIME (rule #20) — runtime indexing
// sent the whole 512B/thread accumulator to scratch (rounds 4-5: 249-279MB
// HBM writes). Merge epilogue selects by VALUE (mh ? a : b), never by index.
#define KT 64
#define NT (M_ / KT)   // 32

__global__ __launch_bounds__(512, 1) void attn_kernel(
    const bf16_t* __restrict__ qb, const bf16_t* __restrict__ kb, const bf16_t* __restrict__ vb,
    const float* __restrict__ x, const float* __restrict__ gate, float* __restrict__ out) {
    // LDS: K 2x32KB | V 2x32KB = 128KB (reused as merge buffer) ; ml buffer 4KB
    __shared__ __align__(16) char smem[135168];
    char* Kbase_l = smem;
    char* Vbase_l = smem + 65536;

    const int t = threadIdx.x;
    const int wave = t >> 6, lane = t & 63;
    const int qg = wave & 3, mh = wave >> 2;
    const int l31 = lane & 31, hi = lane >> 5;
    const int bid = blockIdx.x;
    const int b = bid & 7;          // batch -> XCD affinity
    const int lt = bid >> 3;        // 0..31
    const int l0w = lt * 128 + qg * 32;

    // ---- staging geometry (global source pre-swizzled, LDS dest linear) ----
    const char* Kg = (const char*)(kb + (size_t)b * M_ * C_);
    const char* Vg = (const char*)(vb + (size_t)b * C_ * M_);
    int ksrc[4], vsrc[4];
#pragma unroll
    for (int i = 0; i < 4; ++i) {
        int chunk = i * 8 + wave;                 // 0..31 (1KB LDS chunks)
        int mr = chunk * 2 + (lane >> 5);         // K row 0..63
        ksrc[i] = mr * 512 + (((lane & 31) * 16) ^ ((mr & 7) << 4));
        int c = chunk * 8 + (lane >> 3);          // V row 0..255
        vsrc[i] = c * (M_ * 2) + (((lane & 7) * 16) ^ ((c & 7) << 4));
    }

    // ---- prologue: stage tile 0 into buffer 0 ----
#pragma unroll
    for (int i = 0; i < 4; ++i)
        gload_lds16(Kg + ksrc[i], Kbase_l + (i * 8 + wave) * 1024);
#pragma unroll
    for (int i = 0; i < 4; ++i)
        gload_lds16(Vg + vsrc[i], Vbase_l + (i * 8 + wave) * 1024);

    // ---- Q fragments in registers: qf[ks] = Q[l0w + l31][ks*16 + hi*8 .. +8] ----
    bf16x8 qf[16];
    const bf16_t* Qp = qb + ((size_t)(b * L_ + l0w + l31) * C_) + hi * 8;
#pragma unroll
    for (int ks = 0; ks < 16; ++ks) qf[ks] = *ldg8(Qp + ks * 16);

    f32x16 acc[8];
#pragma unroll
    for (int cb = 0; cb < 8; ++cb)
#pragma unroll
        for (int r = 0; r < 16; ++r) acc[cb][r] = 0.f;
    float m_run = -INFINITY, l_run = 0.f;

    asm volatile("s_waitcnt vmcnt(0)" ::: "memory");
    __builtin_amdgcn_s_barrier();
    asm volatile("" ::: "memory");

    for (int kt = 0; kt < NT; ++kt) {
        const int cur = kt & 1;
        // ---- issue DMA for tile kt+1 into other buffers ----
        if (kt + 1 < NT) {
            const char* Kn = Kg + (size_t)(kt + 1) * 32768;
            char* Kd = Kbase_l + (cur ^ 1) * 32768;
#pragma unroll
            for (int i = 0; i < 4; ++i)
                gload_lds16(Kn + ksrc[i], Kd + (i * 8 + wave) * 1024);
            const char* Vn = Vg + (size_t)(kt + 1) * 128;   // m-offset in bytes
            char* Vd = Vbase_l + (cur ^ 1) * 32768;
#pragma unroll
            for (int i = 0; i < 4; ++i)
                gload_lds16(Vn + vsrc[i], Vd + (i * 8 + wave) * 1024);
        }

        // ---- S = K' x Q : D[m,l] for this wave's m-half (rows mh*32 + 0..31) ----
        const char* Kc = Kbase_l + cur * 32768;
        const int mrow = mh * 32 + l31;
        const int msw = (mrow & 7) << 4;
        const int moff = mrow * 512;
        f32x16 s;
#pragma unroll
        for (int r = 0; r < 16; ++r) s[r] = 0.f;
        __builtin_amdgcn_s_setprio(1);
#pragma unroll
        for (int ks = 0; ks < 16; ++ks) {
            int cb2 = ks * 32 + hi * 16;
            bf16x8 a = *reinterpret_cast<const bf16x8*>(Kc + moff + (cb2 ^ msw));
            s = __builtin_amdgcn_mfma_f32_32x32x16_bf16(a, qf[ks], s, 0, 0, 0);
        }
        __builtin_amdgcn_s_setprio(0);

        // ---- online softmax over this m-half; lanes l and l+32 share query l ----
        float pv[16];
        float tm = -INFINITY;
#pragma unroll
        for (int r = 0; r < 16; ++r) {
            float v0 = s[r] * 0.0625f;
            pv[r] = v0;
            tm = fmaxf(tm, v0);
        }
        tm = fmaxf(tm, __shfl_xor(tm, 32));
        if (!__all(tm - m_run <= 8.0f)) {           // defer-max (T13)
            float m_new = fmaxf(m_run, tm);
            float corr = __expf(m_run - m_new);
#pragma unroll
            for (int cb = 0; cb < 8; ++cb)
#pragma unroll
                for (int r = 0; r < 16; ++r) acc[cb][r] *= corr;
            l_run *= corr;
            m_run = m_new;
        }
        float rs = 0.f;
#pragma unroll
        for (int i = 0; i < 16; ++i) { pv[i] = __expf(pv[i] - m_run); rs += pv[i]; }
        l_run += rs + __shfl_xor(rs, 32);

        // ---- build P B-frags in registers (k = m_local 0..31) ----
        union PW { unsigned u[4]; bf16x8 v; };
        bf16x8 pfrag[2];
        {
            unsigned Ce0 = packbf(pv[0], pv[1]);
            unsigned Ce1 = packbf(pv[2], pv[3]);
            unsigned Ce2 = packbf(pv[4], pv[5]);
            unsigned Ce3 = packbf(pv[6], pv[7]);
            unsigned Co0 = packbf(pv[8], pv[9]);
            unsigned Co1 = packbf(pv[10], pv[11]);
            unsigned Co2 = packbf(pv[12], pv[13]);
            unsigned Co3 = packbf(pv[14], pv[15]);
            unsigned Xe0 = (unsigned)__shfl_xor((int)Ce0, 32);
            unsigned Xe1 = (unsigned)__shfl_xor((int)Ce1, 32);
            unsigned Xe2 = (unsigned)__shfl_xor((int)Ce2, 32);
            unsigned Xe3 = (unsigned)__shfl_xor((int)Ce3, 32);
            unsigned Xo0 = (unsigned)__shfl_xor((int)Co0, 32);
            unsigned Xo1 = (unsigned)__shfl_xor((int)Co1, 32);
            unsigned Xo2 = (unsigned)__shfl_xor((int)Co2, 32);
            unsigned Xo3 = (unsigned)__shfl_xor((int)Co3, 32);
            PW we, wo;
            we.u[0] = hi ? Xe2 : Ce0;
            we.u[1] = hi ? Xe3 : Ce1;
            we.u[2] = hi ? Ce2 : Xe0;
            we.u[3] = hi ? Ce3 : Xe1;
            wo.u[0] = hi ? Xo2 : Co0;
            wo.u[1] = hi ? Xo3 : Co1;
            wo.u[2] = hi ? Co2 : Xo0;
            wo.u[3] = hi ? Co3 : Xo1;
            pfrag[0] = we.v;
            pfrag[1] = wo.v;
        }

        // ---- PV: D[c,l] += V[c,m] * P[m,l] over this wave's m-half ----
        const char* Vc = Vbase_l + cur * 32768;
        __builtin_amdgcn_s_setprio(1);
#pragma unroll
        for (int ks2 = 0; ks2 < 2; ++ks2) {
            int cb2 = (mh * 2 + ks2) * 32 + hi * 16;
#pragma unroll
            for (int cb = 0; cb < 8; ++cb) {
                int c = cb * 32 + l31;
                bf16x8 a = *reinterpret_cast<const bf16x8*>(Vc + c * 128 + (cb2 ^ ((c & 7) << 4)));
                acc[cb] = __builtin_amdgcn_mfma_f32_32x32x16_bf16(a, pfrag[ks2], acc[cb], 0, 0, 0);
            }
        }
        __builtin_amdgcn_s_setprio(0);

        // ---- publish: my DMAs landed; all waves done before buffer swap ----
        asm volatile("s_waitcnt vmcnt(0)" ::: "memory");
        __builtin_amdgcn_s_barrier();
        asm volatile("" ::: "memory");
    }

    // ---- split-K merge between wave pairs (qg, 0) <-> (qg, 1) ----
    f32x2* mlb = (f32x2*)(smem + 131072);
    f32x2 myml; myml[0] = m_run; myml[1] = l_run;
    mlb[wave * 64 + lane] = myml;
    __syncthreads();
    f32x2 pml = mlb[(wave ^ 4) * 64 + lane];
    float m_star = fmaxf(m_run, pml[0]);
    float f_self = __expf(m_run - m_star);
    float f_peer = __expf(pml[0] - m_star);
    float l_tot = l_run * f_self + pml[1] * f_peer;
#pragma unroll
    for (int cb = 0; cb < 8; ++cb)
#pragma unroll
        for (int r = 0; r < 16; ++r) acc[cb][r] *= f_self;

    // ---- export half (channels of the OTHER mh) to LDS; acc indices STATIC ----
    char* xbuf = smem;
    const int myoff = (qg * 2 + mh) * 16384;
    __syncthreads();   // mlb consumed; K/V buffers dead -> safe to overwrite
#pragma unroll
    for (int cbl = 0; cbl < 4; ++cbl)
#pragma unroll
        for (int q = 0; q < 4; ++q) {
            f32x4 chunk;
#pragma unroll
            for (int j = 0; j < 4; ++j) {
                float a_lo = acc[cbl][q * 4 + j];      // exported when mh==1
                float a_hi = acc[4 + cbl][q * 4 + j];  // exported when mh==0
                chunk[j] = mh ? a_lo : a_hi;
            }
            *reinterpret_cast<f32x4*>(xbuf + myoff + (cbl * 4 + q) * 1024 + lane * 16) = chunk;
        }
    __syncthreads();

    // ---- read partner's export (= my kept channels), finalize, epilogue ----
    const int poff = (qg * 2 + (1 - mh)) * 16384;
    float gt = tanhf(gate[0]);
    float scale = gt / l_tot;
    const float* xp = x + (size_t)b * C_ * L_;
    float* op = out + (size_t)b * C_ * L_;
    int lcol = l0w + l31;
    const int cbase = mh * 4;   // value arithmetic only, never an acc index
#pragma unroll
    for (int cbl = 0; cbl < 4; ++cbl) {
#pragma unroll
        for (int q = 0; q < 4; ++q) {
            f32x4 pc = *reinterpret_cast<const f32x4*>(xbuf + poff + (cbl * 4 + q) * 1024 + lane * 16);
#pragma unroll
            for (int j = 0; j < 4; ++j) {
                float a_lo = acc[cbl][q * 4 + j];      // kept when mh==0
                float a_hi = acc[4 + cbl][q * 4 + j];  // kept when mh==1
                float mine = mh ? a_hi : a_lo;
                int c = (cbase + cbl) * 32 + j + 8 * q + 4 * hi;
                size_t idx = (size_t)c * L_ + lcol;
                op[idx] = (mine + pc[j]) * scale + xp[idx];
            }
        }
    }
}

extern "C" void kernel_launch(void* const* d_in, const int* in_sizes, int n_in,
                              void* d_out, int out_size, void* d_ws, size_t ws_size,
                              hipStream_t stream) {
    const float* x    = (const float*)d_in[0];
    const float* Wq   = (const float*)d_in[1];
    const float* bq   = (const float*)d_in[2];
    const float* Wk   = (const float*)d_in[3];
    const float* bk   = (const float*)d_in[4];
    const float* Wv   = (const float*)d_in[5];
    const float* bv   = (const float*)d_in[6];
    const float* gate = (const float*)d_in[7];
    float* out = (float*)d_out;

    char* ws = (char*)d_ws;
    const size_t szW   = (size_t)C_ * C_ * 2;          // 131072
    const size_t szXbt = (size_t)B_ * L_ * C_ * 2;     // 16777216
    const size_t szXh  = (size_t)B_ * M_ * C_ * 2;     // 8388608
    bf16_t* Wqb  = (bf16_t*)(ws);
    bf16_t* Wkb  = (bf16_t*)(ws + szW);
    bf16_t* Wvb  = (bf16_t*)(ws + 2 * szW);
    bf16_t* xbt  = (bf16_t*)(ws + 3 * szW);
    bf16_t* xhbt = (bf16_t*)(ws + 3 * szW + szXbt);
    bf16_t* qb   = (bf16_t*)(ws + 3 * szW + szXbt + szXh);
    bf16_t* kb   = (bf16_t*)(ws + 3 * szW + 2 * szXbt + szXh);
    bf16_t* vb   = (bf16_t*)(ws + 3 * szW + 2 * szXbt + 2 * szXh);

    conv_w_kernel<<<768, 256, 0, stream>>>(Wq, Wk, Wv, Wqb, Wkb, Wvb);
    prep_x_kernel<<<dim3(L_ / 64, C_ / 64, B_), 256, 0, stream>>>(x, xbt, xhbt);
    proj_nk_kernel<<<dim3(L_ / 64, B_), 256, 0, stream>>>(xbt, Wqb, bq, qb, L_);
    proj_nk_kernel<<<dim3(M_ / 64, B_), 256, 0, stream>>>(xhbt, Wkb, bk, kb, M_);
    proj_v_kernel<<<dim3(M_ / 256, C_ / 64, B_), 256, 0, stream>>>(xhbt, Wvb, bv, vb);
    attn_kernel<<<256, 512, 0, stream>>>(qb, kb, vb, x, gate, out);
}

// Round 7
// 151.756 us; speedup vs baseline: 1.6118x; 1.3122x over previous
//
#include <hip/hip_runtime.h>
#include <hip/hip_bf16.h>

typedef __bf16 bf16_t;
typedef __bf16 bf16x8 __attribute__((ext_vector_type(8)));
typedef float  f32x2  __attribute__((ext_vector_type(2)));
typedef float  f32x4  __attribute__((ext_vector_type(4)));
typedef float  f32x16 __attribute__((ext_vector_type(16)));

#define B_ 8
#define C_ 256
#define L_ 4096
#define M_ 2048
#define INV_SQRT2f 0.70710678118654752440f

typedef __attribute__((address_space(3))) void as3_void;
typedef __attribute__((address_space(1))) const void as1_cvoid;

__device__ __forceinline__ void gload_lds16(const void* g, void* l) {
    __builtin_amdgcn_global_load_lds((as1_cvoid*)g, (as3_void*)l, 16, 0, 0);
}

__device__ __forceinline__ unsigned packbf(float a, float b) {
    unsigned short ua = __builtin_bit_cast(unsigned short, (bf16_t)a);
    unsigned short ub = __builtin_bit_cast(unsigned short, (bf16_t)b);
    return (unsigned)ua | ((unsigned)ub << 16);
}

// load 8 consecutive f32, convert to bf16x8 (RNE via cast)
__device__ __forceinline__ bf16x8 cvt8(const float* p) {
    f32x4 a = *reinterpret_cast<const f32x4*>(p);
    f32x4 b = *reinterpret_cast<const f32x4*>(p + 4);
    union { unsigned u[4]; bf16x8 v; } w;
    w.u[0] = packbf(a[0], a[1]);
    w.u[1] = packbf(a[2], a[3]);
    w.u[2] = packbf(b[0], b[1]);
    w.u[3] = packbf(b[2], b[3]);
    return w.v;
}

// ================= kernel A: fused Haar + K-proj + V-proj =================
// Per block (b, mt): xh[64 m][256 c] bf16 in LDS (swizzled), then
//   k'[B,M,C]: D[m][o] = mfma(A=xh rows, B=Wk rows)  + bk
//   v'[B,C,M]: D[o][m] = mfma(A=Wv rows, B=xh rows)  + bv
// Weights converted f32->bf16 inline (L2-resident).
__global__ __launch_bounds__(256, 1) void kv_proj_kernel(
    const float* __restrict__ x, const float* __restrict__ Wk, const float* __restrict__ bk,
    const float* __restrict__ Wv, const float* __restrict__ bv,
    bf16_t* __restrict__ kb, bf16_t* __restrict__ vb) {
    __shared__ __align__(16) char smem[32768 + 33280];
    char* xh = smem;                           // [64][512B] swizzled
    float* tile = (float*)(smem + 32768);      // f32 [64][130]

    const int t = threadIdx.x;
    const int wave = t >> 6, lane = t & 63;
    const int l31 = lane & 31, hi = lane >> 5;
    const int bid = blockIdx.x;
    const int b = bid & 7;
    const int mt = bid >> 3;        // 0..31
    const int m0 = mt * 64;

    // ---- phase 1: build xh (4 c-chunks of 64) ----
    for (int cc = 0; cc < 4; ++cc) {
        if (cc) __syncthreads();   // previous chunk's tile readers done
        const float* xs = x + ((size_t)(b * C_ + cc * 64) * L_) + 2 * m0;
#pragma unroll
        for (int j = 0; j < 16; ++j) {
            int e = t + j * 256;
            int row = e >> 6, cp = e & 63;
            f32x2 v = *reinterpret_cast<const f32x2*>(xs + (size_t)row * L_ + cp * 2);
            *reinterpret_cast<f32x2*>(tile + row * 130 + cp * 2) = v;
        }
        __syncthreads();
        int cpr = t & 63;              // this thread's c within chunk
        int mbase = (t >> 6) * 16;     // 16 m-rows per wave
#pragma unroll
        for (int i = 0; i < 16; ++i) {
            int m = mbase + i;
            f32x2 p = *reinterpret_cast<const f32x2*>(tile + cpr * 130 + 2 * m);
            float v = (p[0] - p[1]) * INV_SQRT2f;
            int byte = m * 512 + ((((cc * 64 + cpr) * 2)) ^ ((m & 7) << 4));
            *reinterpret_cast<bf16_t*>(xh + byte) = (bf16_t)v;
        }
    }
    __syncthreads();

    // ---- phase 2: K-proj. wave -> (mblk = w&1, ohalf = w>>1) ----
    {
        const int mblk = wave & 1;
        const int ohalf = wave >> 1;
        f32x16 kacc[4];
#pragma unroll
        for (int ob = 0; ob < 4; ++ob) {
            float bko = bk[(ohalf * 4 + ob) * 32 + l31];
#pragma unroll
            for (int r = 0; r < 16; ++r) kacc[ob][r] = bko;
        }
        const int arow = mblk * 32 + l31;
        const int aswz = (arow & 7) << 4;
#pragma unroll
        for (int ks = 0; ks < 16; ++ks) {
            bf16x8 a = *reinterpret_cast<const bf16x8*>(
                xh + arow * 512 + (((ks * 16 + hi * 8) * 2) ^ aswz));
#pragma unroll
            for (int ob = 0; ob < 4; ++ob) {
                int o = (ohalf * 4 + ob) * 32 + l31;
                bf16x8 bw = cvt8(Wk + (size_t)o * C_ + ks * 16 + hi * 8);
                kacc[ob] = __builtin_amdgcn_mfma_f32_32x32x16_bf16(a, bw, kacc[ob], 0, 0, 0);
            }
        }
        bf16_t* kout = kb + (size_t)b * M_ * C_;
#pragma unroll
        for (int ob = 0; ob < 4; ++ob) {
            int o = (ohalf * 4 + ob) * 32 + l31;
#pragma unroll
            for (int r = 0; r < 16; ++r) {
                int mloc = mblk * 32 + (r & 3) + 8 * (r >> 2) + 4 * hi;
                kout[(size_t)(m0 + mloc) * C_ + o] = (bf16_t)kacc[ob][r];
            }
        }
    }

    // ---- phase 3: V-proj. wave -> o-blocks {2w, 2w+1} x mblk {0,1} ----
    {
        f32x16 vacc[4];
#pragma unroll
        for (int i2 = 0; i2 < 4; ++i2)
#pragma unroll
            for (int r = 0; r < 16; ++r) vacc[i2][r] = 0.f;
        const int r0 = l31, r1 = 32 + l31;
        const int s0 = (r0 & 7) << 4, s1 = (r1 & 7) << 4;
#pragma unroll
        for (int ks = 0; ks < 16; ++ks) {
            int cb = (ks * 16 + hi * 8) * 2;
            bf16x8 bx0 = *reinterpret_cast<const bf16x8*>(xh + r0 * 512 + (cb ^ s0));
            bf16x8 bx1 = *reinterpret_cast<const bf16x8*>(xh + r1 * 512 + (cb ^ s1));
#pragma unroll
            for (int oi = 0; oi < 2; ++oi) {
                int orow = (wave * 2 + oi) * 32 + l31;
                bf16x8 aw = cvt8(Wv + (size_t)orow * C_ + ks * 16 + hi * 8);
                vacc[oi * 2 + 0] = __builtin_amdgcn_mfma_f32_32x32x16_bf16(aw, bx0, vacc[oi * 2 + 0], 0, 0, 0);
                vacc[oi * 2 + 1] = __builtin_amdgcn_mfma_f32_32x32x16_bf16(aw, bx1, vacc[oi * 2 + 1], 0, 0, 0);
            }
        }
        bf16_t* vout = vb + (size_t)b * C_ * M_;
#pragma unroll
        for (int oi = 0; oi < 2; ++oi)
#pragma unroll
            for (int mb2 = 0; mb2 < 2; ++mb2)
#pragma unroll
                for (int r = 0; r < 16; ++r) {
                    int o = (wave * 2 + oi) * 32 + (r & 3) + 8 * (r >> 2) + 4 * hi;
                    vout[(size_t)o * M_ + m0 + mb2 * 32 + l31] = (bf16_t)(vacc[oi * 2 + mb2][r] + bv[o]);
                }
    }
}

// ================= kernel B: attention with fused Q-projection =================
#define KT 64
#define NT (M_ / KT)   // 32

__global__ __launch_bounds__(512, 1) void attn_kernel(
    const float* __restrict__ Wq, const float* __restrict__ bq,
    const bf16_t* __restrict__ kb, const bf16_t* __restrict__ vb,
    const float* __restrict__ x, const float* __restrict__ gate, float* __restrict__ out) {
    // LDS: K 2x32KB | V 2x32KB = 128KB (prologue: xt in K-space, f32 tile/qt in V-space)
    __shared__ __align__(16) char smem[135168];
    char* Kbase_l = smem;
    char* Vbase_l = smem + 65536;

    const int t = threadIdx.x;
    const int wave = t >> 6, lane = t & 63;
    const int qg = wave & 3, mh = wave >> 2;
    const int l31 = lane & 31, hi = lane >> 5;
    const int bid = blockIdx.x;
    const int b = bid & 7;          // batch -> XCD affinity
    const int lt = bid >> 3;        // 0..31
    const int l0w = lt * 128 + qg * 32;

    bf16x8 qf[16];

    // ======== Q-projection prologue ========
    {
        float* tile = (float*)Vbase_l;   // f32 [64][130]
        char* xt = Kbase_l;              // [128][512B] bf16 swizzled
        for (int cc = 0; cc < 4; ++cc) {
            if (cc) __syncthreads();
            const float* xs = x + ((size_t)(b * C_ + cc * 64) * L_) + lt * 128;
#pragma unroll
            for (int j = 0; j < 8; ++j) {
                int e = t + j * 512;
                int row = e >> 6, cp = e & 63;
                f32x2 v = *reinterpret_cast<const f32x2*>(xs + (size_t)row * L_ + cp * 2);
                *reinterpret_cast<f32x2*>(tile + row * 130 + cp * 2) = v;
            }
            __syncthreads();
            int cpr = t & 63;
            int lbase = (t >> 6) * 16;
#pragma unroll
            for (int i = 0; i < 16; ++i) {
                int l = lbase + i;
                float v = tile[cpr * 130 + l];
                int byte = l * 512 + ((((cc * 64 + cpr) * 2)) ^ ((l & 7) << 4));
                *reinterpret_cast<bf16_t*>(xt + byte) = (bf16_t)v;
            }
        }
        __syncthreads();

        // Q-GEMM: D[o][l]; wave's o-block = wave*32; l-blocks 0..3
        const int ow = wave * 32;
        f32x16 qacc[4];
#pragma unroll
        for (int lb = 0; lb < 4; ++lb)
#pragma unroll
            for (int r = 0; r < 16; ++r) qacc[lb][r] = 0.f;
#pragma unroll
        for (int ks = 0; ks < 16; ++ks) {
            bf16x8 aw = cvt8(Wq + (size_t)(ow + l31) * C_ + ks * 16 + hi * 8);
#pragma unroll
            for (int lb = 0; lb < 4; ++lb) {
                int lrow = lb * 32 + l31;
                bf16x8 bx = *reinterpret_cast<const bf16x8*>(
                    xt + lrow * 512 + (((ks * 16 + hi * 8) * 2) ^ ((lrow & 7) << 4)));
                qacc[lb] = __builtin_amdgcn_mfma_f32_32x32x16_bf16(aw, bx, qacc[lb], 0, 0, 0);
            }
        }
        __syncthreads();   // all xt reads & tile use done; V-space becomes qt
        char* qt = Vbase_l;  // [128][512B] bf16 swizzled
#pragma unroll
        for (int lb = 0; lb < 4; ++lb) {
            int l = lb * 32 + l31;
            int lsw = (l & 7) << 4;
#pragma unroll
            for (int q = 0; q < 4; ++q) {
                int o = ow + 4 * hi + 8 * q;
                f32x4 bq4 = *reinterpret_cast<const f32x4*>(bq + o);
                unsigned w0 = packbf(qacc[lb][q * 4 + 0] + bq4[0], qacc[lb][q * 4 + 1] + bq4[1]);
                unsigned w1 = packbf(qacc[lb][q * 4 + 2] + bq4[2], qacc[lb][q * 4 + 3] + bq4[3]);
                unsigned long long w = (unsigned long long)w0 | ((unsigned long long)w1 << 32);
                *reinterpret_cast<unsigned long long*>(qt + l * 512 + ((o * 2) ^ lsw)) = w;
            }
        }
        __syncthreads();
        const int qrow = qg * 32 + l31;
        const int qswz = (qrow & 7) << 4;
#pragma unroll
        for (int ks = 0; ks < 16; ++ks)
            qf[ks] = *reinterpret_cast<const bf16x8*>(
                qt + qrow * 512 + (((ks * 16 + hi * 8) * 2) ^ qswz));
        __syncthreads();   // qf read everywhere; K/V DMA may now overwrite
    }

    // ======== main flash loop (unchanged from round 6) ========
    const char* Kg = (const char*)(kb + (size_t)b * M_ * C_);
    const char* Vg = (const char*)(vb + (size_t)b * C_ * M_);
    int ksrc[4], vsrc[4];
#pragma unroll
    for (int i = 0; i < 4; ++i) {
        int chunk = i * 8 + wave;
        int mr = chunk * 2 + (lane >> 5);
        ksrc[i] = mr * 512 + (((lane & 31) * 16) ^ ((mr & 7) << 4));
        int c = chunk * 8 + (lane >> 3);
        vsrc[i] = c * (M_ * 2) + (((lane & 7) * 16) ^ ((c & 7) << 4));
    }

#pragma unroll
    for (int i = 0; i < 4; ++i)
        gload_lds16(Kg + ksrc[i], Kbase_l + (i * 8 + wave) * 1024);
#pragma unroll
    for (int i = 0; i < 4; ++i)
        gload_lds16(Vg + vsrc[i], Vbase_l + (i * 8 + wave) * 1024);

    f32x16 acc[8];
#pragma unroll
    for (int cb = 0; cb < 8; ++cb)
#pragma unroll
        for (int r = 0; r < 16; ++r) acc[cb][r] = 0.f;
    float m_run = -INFINITY, l_run = 0.f;

    asm volatile("s_waitcnt vmcnt(0)" ::: "memory");
    __builtin_amdgcn_s_barrier();
    asm volatile("" ::: "memory");

    for (int kt = 0; kt < NT; ++kt) {
        const int cur = kt & 1;
        if (kt + 1 < NT) {
            const char* Kn = Kg + (size_t)(kt + 1) * 32768;
            char* Kd = Kbase_l + (cur ^ 1) * 32768;
#pragma unroll
            for (int i = 0; i < 4; ++i)
                gload_lds16(Kn + ksrc[i], Kd + (i * 8 + wave) * 1024);
            const char* Vn = Vg + (size_t)(kt + 1) * 128;
            char* Vd = Vbase_l + (cur ^ 1) * 32768;
#pragma unroll
            for (int i = 0; i < 4; ++i)
                gload_lds16(Vn + vsrc[i], Vd + (i * 8 + wave) * 1024);
        }

        const char* Kc = Kbase_l + cur * 32768;
        const int mrow = mh * 32 + l31;
        const int msw = (mrow & 7) << 4;
        const int moff = mrow * 512;
        f32x16 s;
#pragma unroll
        for (int r = 0; r < 16; ++r) s[r] = 0.f;
        __builtin_amdgcn_s_setprio(1);
#pragma unroll
        for (int ks = 0; ks < 16; ++ks) {
            int cb2 = ks * 32 + hi * 16;
            bf16x8 a = *reinterpret_cast<const bf16x8*>(Kc + moff + (cb2 ^ msw));
            s = __builtin_amdgcn_mfma_f32_32x32x16_bf16(a, qf[ks], s, 0, 0, 0);
        }
        __builtin_amdgcn_s_setprio(0);

        float pv[16];
        float tm = -INFINITY;
#pragma unroll
        for (int r = 0; r < 16; ++r) {
            float v0 = s[r] * 0.0625f;
            pv[r] = v0;
            tm = fmaxf(tm, v0);
        }
        tm = fmaxf(tm, __shfl_xor(tm, 32));
        if (!__all(tm - m_run <= 8.0f)) {
            float m_new = fmaxf(m_run, tm);
            float corr = __expf(m_run - m_new);
#pragma unroll
            for (int cb = 0; cb < 8; ++cb)
#pragma unroll
                for (int r = 0; r < 16; ++r) acc[cb][r] *= corr;
            l_run *= corr;
            m_run = m_new;
        }
        float rs = 0.f;
#pragma unroll
        for (int i = 0; i < 16; ++i) { pv[i] = __expf(pv[i] - m_run); rs += pv[i]; }
        l_run += rs + __shfl_xor(rs, 32);

        union PW { unsigned u[4]; bf16x8 v; };
        bf16x8 pfrag[2];
        {
            unsigned Ce0 = packbf(pv[0], pv[1]);
            unsigned Ce1 = packbf(pv[2], pv[3]);
            unsigned Ce2 = packbf(pv[4], pv[5]);
            unsigned Ce3 = packbf(pv[6], pv[7]);
            unsigned Co0 = packbf(pv[8], pv[9]);
            unsigned Co1 = packbf(pv[10], pv[11]);
            unsigned Co2 = packbf(pv[12], pv[13]);
            unsigned Co3 = packbf(pv[14], pv[15]);
            unsigned Xe0 = (unsigned)__shfl_xor((int)Ce0, 32);
            unsigned Xe1 = (unsigned)__shfl_xor((int)Ce1, 32);
            unsigned Xe2 = (unsigned)__shfl_xor((int)Ce2, 32);
            unsigned Xe3 = (unsigned)__shfl_xor((int)Ce3, 32);
            unsigned Xo0 = (unsigned)__shfl_xor((int)Co0, 32);
            unsigned Xo1 = (unsigned)__shfl_xor((int)Co1, 32);
            unsigned Xo2 = (unsigned)__shfl_xor((int)Co2, 32);
            unsigned Xo3 = (unsigned)__shfl_xor((int)Co3, 32);
            PW we, wo;
            we.u[0] = hi ? Xe2 : Ce0;
            we.u[1] = hi ? Xe3 : Ce1;
            we.u[2] = hi ? Ce2 : Xe0;
            we.u[3] = hi ? Ce3 : Xe1;
            wo.u[0] = hi ? Xo2 : Co0;
            wo.u[1] = hi ? Xo3 : Co1;
            wo.u[2] = hi ? Co2 : Xo0;
            wo.u[3] = hi ? Co3 : Xo1;
            pfrag[0] = we.v;
            pfrag[1] = wo.v;
        }

        const char* Vc = Vbase_l + cur * 32768;
        __builtin_amdgcn_s_setprio(1);
#pragma unroll
        for (int ks2 = 0; ks2 < 2; ++ks2) {
            int cb2 = (mh * 2 + ks2) * 32 + hi * 16;
#pragma unroll
            for (int cb = 0; cb < 8; ++cb) {
                int c = cb * 32 + l31;
                bf16x8 a = *reinterpret_cast<const bf16x8*>(Vc + c * 128 + (cb2 ^ ((c & 7) << 4)));
                acc[cb] = __builtin_amdgcn_mfma_f32_32x32x16_bf16(a, pfrag[ks2], acc[cb], 0, 0, 0);
            }
        }
        __builtin_amdgcn_s_setprio(0);

        asm volatile("s_waitcnt vmcnt(0)" ::: "memory");
        __builtin_amdgcn_s_barrier();
        asm volatile("" ::: "memory");
    }

    // ---- split-K merge between wave pairs (qg, 0) <-> (qg, 1) ----
    f32x2* mlb = (f32x2*)(smem + 131072);
    f32x2 myml; myml[0] = m_run; myml[1] = l_run;
    mlb[wave * 64 + lane] = myml;
    __syncthreads();
    f32x2 pml = mlb[(wave ^ 4) * 64 + lane];
    float m_star = fmaxf(m_run, pml[0]);
    float f_self = __expf(m_run - m_star);
    float f_peer = __expf(pml[0] - m_star);
    float l_tot = l_run * f_self + pml[1] * f_peer;
#pragma unroll
    for (int cb = 0; cb < 8; ++cb)
#pragma unroll
        for (int r = 0; r < 16; ++r) acc[cb][r] *= f_self;

    char* xbuf = smem;
    const int myoff = (qg * 2 + mh) * 16384;
    __syncthreads();
#pragma unroll
    for (int cbl = 0; cbl < 4; ++cbl)
#pragma unroll
        for (int q = 0; q < 4; ++q) {
            f32x4 chunk;
#pragma unroll
            for (int j = 0; j < 4; ++j) {
                float a_lo = acc[cbl][q * 4 + j];
                float a_hi = acc[4 + cbl][q * 4 + j];
                chunk[j] = mh ? a_lo : a_hi;
            }
            *reinterpret_cast<f32x4*>(xbuf + myoff + (cbl * 4 + q) * 1024 + lane * 16) = chunk;
        }
    __syncthreads();

    const int poff = (qg * 2 + (1 - mh)) * 16384;
    float gt = tanhf(gate[0]);
    float scale = gt / l_tot;
    const float* xp = x + (size_t)b * C_ * L_;
    float* op = out + (size_t)b * C_ * L_;
    int lcol = l0w + l31;
    const int cbase = mh * 4;
#pragma unroll
    for (int cbl = 0; cbl < 4; ++cbl) {
#pragma unroll
        for (int q = 0; q < 4; ++q) {
            f32x4 pc = *reinterpret_cast<const f32x4*>(xbuf + poff + (cbl * 4 + q) * 1024 + lane * 16);
#pragma unroll
            for (int j = 0; j < 4; ++j) {
                float a_lo = acc[cbl][q * 4 + j];
                float a_hi = acc[4 + cbl][q * 4 + j];
                float mine = mh ? a_hi : a_lo;
                int c = (cbase + cbl) * 32 + j + 8 * q + 4 * hi;
                size_t idx = (size_t)c * L_ + lcol;
                op[idx] = (mine + pc[j]) * scale + xp[idx];
            }
        }
    }
}

extern "C" void kernel_launch(void* const* d_in, const int* in_sizes, int n_in,
                              void* d_out, int out_size, void* d_ws, size_t ws_size,
                              hipStream_t stream) {
    const float* x    = (const float*)d_in[0];
    const float* Wq   = (const float*)d_in[1];
    const float* bq   = (const float*)d_in[2];
    const float* Wk   = (const float*)d_in[3];
    const float* bk   = (const float*)d_in[4];
    const float* Wv   = (const float*)d_in[5];
    const float* bv   = (const float*)d_in[6];
    const float* gate = (const float*)d_in[7];
    float* out = (float*)d_out;

    char* ws = (char*)d_ws;
    const size_t szKV = (size_t)B_ * M_ * C_ * 2;   // 8388608
    bf16_t* kbuf = (bf16_t*)(ws);
    bf16_t* vbuf = (bf16_t*)(ws + szKV);

    kv_proj_kernel<<<256, 256, 0, stream>>>(x, Wk, bk, Wv, bv, kbuf, vbuf);
    attn_kernel<<<256, 512, 0, stream>>>(Wq, bq, kbuf, vbuf, x, gate, out);
}

// Round 9
// 138.725 us; speedup vs baseline: 1.7632x; 1.0939x over previous
//
#include <hip/hip_runtime.h>
#include <hip/hip_bf16.h>

typedef __bf16 bf16_t;
typedef __bf16 bf16x8 __attribute__((ext_vector_type(8)));
typedef float  f32x2  __attribute__((ext_vector_type(2)));
typedef float  f32x4  __attribute__((ext_vector_type(4)));
typedef float  f32x16 __attribute__((ext_vector_type(16)));

#define B_ 8
#define C_ 256
#define L_ 4096
#define M_ 2048
#define INV_SQRT2f 0.70710678118654752440f

typedef __attribute__((address_space(3))) void as3_void;
typedef __attribute__((address_space(1))) const void as1_cvoid;

__device__ __forceinline__ void gload_lds16(const void* g, void* l) {
    __builtin_amdgcn_global_load_lds((as1_cvoid*)g, (as3_void*)l, 16, 0, 0);
}

__device__ __forceinline__ unsigned packbf(float a, float b) {
    unsigned short ua = __builtin_bit_cast(unsigned short, (bf16_t)a);
    unsigned short ub = __builtin_bit_cast(unsigned short, (bf16_t)b);
    return (unsigned)ua | ((unsigned)ub << 16);
}

// v_permlane32_swap_b32: a <- [a.lo | b.lo], b <- [a.hi | b.hi]  (VALU, no LDS)
// ONLY safe on operands with DISTINCT values (identical values coalesce into
// one register -> self-swap garbage; cost us round 8's softmax reduce).
__device__ __forceinline__ void pl32swapu(unsigned &a, unsigned &b) {
    asm("v_permlane32_swap_b32 %0, %1" : "+v"(a), "+v"(b));
}

// load 8 consecutive f32, convert to bf16x8 (RNE via cast)
__device__ __forceinline__ bf16x8 cvt8(const float* p) {
    f32x4 a = *reinterpret_cast<const f32x4*>(p);
    f32x4 b = *reinterpret_cast<const f32x4*>(p + 4);
    union { unsigned u[4]; bf16x8 v; } w;
    w.u[0] = packbf(a[0], a[1]);
    w.u[1] = packbf(a[2], a[3]);
    w.u[2] = packbf(b[0], b[1]);
    w.u[3] = packbf(b[2], b[3]);
    return w.v;
}

// ================= kernel A: fused Haar + K-proj + V-proj =================
__global__ __launch_bounds__(256, 1) void kv_proj_kernel(
    const float* __restrict__ x, const float* __restrict__ Wk, const float* __restrict__ bk,
    const float* __restrict__ Wv, const float* __restrict__ bv,
    bf16_t* __restrict__ kb, bf16_t* __restrict__ vb) {
    __shared__ __align__(16) char smem[32768 + 33280];
    char* xh = smem;                           // [64][512B] swizzled
    float* tile = (float*)(smem + 32768);      // f32 [64][130]

    const int t = threadIdx.x;
    const int wave = t >> 6, lane = t & 63;
    const int l31 = lane & 31, hi = lane >> 5;
    const int bid = blockIdx.x;
    const int b = bid & 7;
    const int mt = bid >> 3;        // 0..31
    const int m0 = mt * 64;

    // ---- phase 1: build xh (4 c-chunks of 64), packed 4B writes ----
    const int cp2 = (t & 31) * 2;   // c-pair base within chunk
    const int mg = t >> 5;          // 0..7
    for (int cc = 0; cc < 4; ++cc) {
        if (cc) __syncthreads();
        const float* xs = x + ((size_t)(b * C_ + cc * 64) * L_) + 2 * m0;
#pragma unroll
        for (int j = 0; j < 16; ++j) {
            int e = t + j * 256;
            int row = e >> 6, cp = e & 63;
            f32x2 v = *reinterpret_cast<const f32x2*>(xs + (size_t)row * L_ + cp * 2);
            *reinterpret_cast<f32x2*>(tile + row * 130 + cp * 2) = v;
        }
        __syncthreads();
#pragma unroll
        for (int i = 0; i < 8; ++i) {
            int m = mg * 8 + i;
            f32x2 pa = *reinterpret_cast<const f32x2*>(tile + cp2 * 130 + 2 * m);
            f32x2 pb = *reinterpret_cast<const f32x2*>(tile + (cp2 + 1) * 130 + 2 * m);
            float va = (pa[0] - pa[1]) * INV_SQRT2f;
            float vb2 = (pb[0] - pb[1]) * INV_SQRT2f;
            int byte = m * 512 + ((((cc * 64 + cp2) * 2)) ^ ((m & 7) << 4));
            *reinterpret_cast<unsigned*>(xh + byte) = packbf(va, vb2);
        }
    }
    __syncthreads();

    // ---- phase 2: K-proj. wave -> distinct o-quarter, both m-blocks ----
    {
        const int oq = wave;           // 0..3
        f32x16 kacc[4];                // [ob(2)][mblk(2)]
#pragma unroll
        for (int ob = 0; ob < 2; ++ob) {
            float bko = bk[(oq * 2 + ob) * 32 + l31];
#pragma unroll
            for (int r = 0; r < 16; ++r) { kacc[ob * 2 + 0][r] = bko; kacc[ob * 2 + 1][r] = bko; }
        }
        const int s0 = (l31 & 7) << 4, s1 = ((32 + l31) & 7) << 4;
#pragma unroll
        for (int ks = 0; ks < 16; ++ks) {
            int cb = (ks * 16 + hi * 8) * 2;
            bf16x8 a0 = *reinterpret_cast<const bf16x8*>(xh + l31 * 512 + (cb ^ s0));
            bf16x8 a1 = *reinterpret_cast<const bf16x8*>(xh + (32 + l31) * 512 + (cb ^ s1));
#pragma unroll
            for (int ob = 0; ob < 2; ++ob) {
                int o = (oq * 2 + ob) * 32 + l31;
                bf16x8 bw = cvt8(Wk + (size_t)o * C_ + ks * 16 + hi * 8);
                kacc[ob * 2 + 0] = __builtin_amdgcn_mfma_f32_32x32x16_bf16(a0, bw, kacc[ob * 2 + 0], 0, 0, 0);
                kacc[ob * 2 + 1] = __builtin_amdgcn_mfma_f32_32x32x16_bf16(a1, bw, kacc[ob * 2 + 1], 0, 0, 0);
            }
        }
        bf16_t* kout = kb + (size_t)b * M_ * C_;
#pragma unroll
        for (int ob = 0; ob < 2; ++ob) {
            int o = (oq * 2 + ob) * 32 + l31;
#pragma unroll
            for (int mb2 = 0; mb2 < 2; ++mb2)
#pragma unroll
                for (int r = 0; r < 16; ++r) {
                    int mloc = mb2 * 32 + (r & 3) + 8 * (r >> 2) + 4 * hi;
                    kout[(size_t)(m0 + mloc) * C_ + o] = (bf16_t)kacc[ob * 2 + mb2][r];
                }
        }
    }

    // ---- phase 3: V-proj. wave -> o-blocks {2w, 2w+1} x mblk {0,1} ----
    {
        f32x16 vacc[4];
#pragma unroll
        for (int i2 = 0; i2 < 4; ++i2)
#pragma unroll
            for (int r = 0; r < 16; ++r) vacc[i2][r] = 0.f;
        const int r0 = l31, r1 = 32 + l31;
        const int s0 = (r0 & 7) << 4, s1 = (r1 & 7) << 4;
#pragma unroll
        for (int ks = 0; ks < 16; ++ks) {
            int cb = (ks * 16 + hi * 8) * 2;
            bf16x8 bx0 = *reinterpret_cast<const bf16x8*>(xh + r0 * 512 + (cb ^ s0));
            bf16x8 bx1 = *reinterpret_cast<const bf16x8*>(xh + r1 * 512 + (cb ^ s1));
#pragma unroll
            for (int oi = 0; oi < 2; ++oi) {
                int orow = (wave * 2 + oi) * 32 + l31;
                bf16x8 aw = cvt8(Wv + (size_t)orow * C_ + ks * 16 + hi * 8);
                vacc[oi * 2 + 0] = __builtin_amdgcn_mfma_f32_32x32x16_bf16(aw, bx0, vacc[oi * 2 + 0], 0, 0, 0);
                vacc[oi * 2 + 1] = __builtin_amdgcn_mfma_f32_32x32x16_bf16(aw, bx1, vacc[oi * 2 + 1], 0, 0, 0);
            }
        }
        bf16_t* vout = vb + (size_t)b * C_ * M_;
#pragma unroll
        for (int oi = 0; oi < 2; ++oi)
#pragma unroll
            for (int mb2 = 0; mb2 < 2; ++mb2)
#pragma unroll
                for (int r = 0; r < 16; ++r) {
                    int o = (wave * 2 + oi) * 32 + (r & 3) + 8 * (r >> 2) + 4 * hi;
                    vout[(size_t)o * M_ + m0 + mb2 * 32 + l31] = (bf16_t)(vacc[oi * 2 + mb2][r] + bv[o]);
                }
    }
}

// ================= kernel B: attention with fused Q-projection =================
#define KT 64
#define NT (M_ / KT)   // 32

__global__ __launch_bounds__(512, 1) void attn_kernel(
    const float* __restrict__ Wq, const float* __restrict__ bq,
    const bf16_t* __restrict__ kb, const bf16_t* __restrict__ vb,
    const float* __restrict__ x, const float* __restrict__ gate, float* __restrict__ out) {
    __shared__ __align__(16) char smem[135168];
    char* Kbase_l = smem;
    char* Vbase_l = smem + 65536;

    const int t = threadIdx.x;
    const int wave = t >> 6, lane = t & 63;
    const int qg = wave & 3, mh = wave >> 2;
    const int l31 = lane & 31, hi = lane >> 5;
    const int bid = blockIdx.x;
    const int b = bid & 7;          // batch -> XCD affinity
    const int lt = bid >> 3;        // 0..31
    const int l0w = lt * 128 + qg * 32;

    bf16x8 qf[16];

    // ======== Q-projection prologue (scale 1/sqrt(C) folded into q; exact 2^-4) ========
    {
        float* tile = (float*)Vbase_l;   // f32 [64][130]
        char* xt = Kbase_l;              // [128][512B] bf16 swizzled
        const int cp2 = (t & 31) * 2;
        const int lg = t >> 5;           // 0..15
        for (int cc = 0; cc < 4; ++cc) {
            if (cc) __syncthreads();
            const float* xs = x + ((size_t)(b * C_ + cc * 64) * L_) + lt * 128;
#pragma unroll
            for (int j = 0; j < 8; ++j) {
                int e = t + j * 512;
                int row = e >> 6, cp = e & 63;
                f32x2 v = *reinterpret_cast<const f32x2*>(xs + (size_t)row * L_ + cp * 2);
                *reinterpret_cast<f32x2*>(tile + row * 130 + cp * 2) = v;
            }
            __syncthreads();
#pragma unroll
            for (int i = 0; i < 8; ++i) {
                int l = lg * 8 + i;
                float va = tile[cp2 * 130 + l];
                float vb2 = tile[(cp2 + 1) * 130 + l];
                int byte = l * 512 + ((((cc * 64 + cp2) * 2)) ^ ((l & 7) << 4));
                *reinterpret_cast<unsigned*>(xt + byte) = packbf(va, vb2);
            }
        }
        __syncthreads();

        const int ow = wave * 32;
        f32x16 qacc[4];
#pragma unroll
        for (int lb = 0; lb < 4; ++lb)
#pragma unroll
            for (int r = 0; r < 16; ++r) qacc[lb][r] = 0.f;
#pragma unroll
        for (int ks = 0; ks < 16; ++ks) {
            bf16x8 aw = cvt8(Wq + (size_t)(ow + l31) * C_ + ks * 16 + hi * 8);
#pragma unroll
            for (int lb = 0; lb < 4; ++lb) {
                int lrow = lb * 32 + l31;
                bf16x8 bx = *reinterpret_cast<const bf16x8*>(
                    xt + lrow * 512 + (((ks * 16 + hi * 8) * 2) ^ ((lrow & 7) << 4)));
                qacc[lb] = __builtin_amdgcn_mfma_f32_32x32x16_bf16(aw, bx, qacc[lb], 0, 0, 0);
            }
        }
        __syncthreads();   // all xt reads & tile use done; V-space becomes qt
        char* qt = Vbase_l;  // [128][512B] bf16 swizzled, holds q*scale
#pragma unroll
        for (int lb = 0; lb < 4; ++lb) {
            int l = lb * 32 + l31;
            int lsw = (l & 7) << 4;
#pragma unroll
            for (int q = 0; q < 4; ++q) {
                int o = ow + 4 * hi + 8 * q;
                f32x4 bq4 = *reinterpret_cast<const f32x4*>(bq + o);
                unsigned w0 = packbf((qacc[lb][q * 4 + 0] + bq4[0]) * 0.0625f,
                                     (qacc[lb][q * 4 + 1] + bq4[1]) * 0.0625f);
                unsigned w1 = packbf((qacc[lb][q * 4 + 2] + bq4[2]) * 0.0625f,
                                     (qacc[lb][q * 4 + 3] + bq4[3]) * 0.0625f);
                unsigned long long w = (unsigned long long)w0 | ((unsigned long long)w1 << 32);
                *reinterpret_cast<unsigned long long*>(qt + l * 512 + ((o * 2) ^ lsw)) = w;
            }
        }
        __syncthreads();
        const int qrow = qg * 32 + l31;
        const int qswz = (qrow & 7) << 4;
#pragma unroll
        for (int ks = 0; ks < 16; ++ks)
            qf[ks] = *reinterpret_cast<const bf16x8*>(
                qt + qrow * 512 + (((ks * 16 + hi * 8) * 2) ^ qswz));
        __syncthreads();   // qf read everywhere; K/V DMA may now overwrite
    }

    // ======== main flash loop ========
    const char* Kg = (const char*)(kb + (size_t)b * M_ * C_);
    const char* Vg = (const char*)(vb + (size_t)b * C_ * M_);
    int ksrc[4], vsrc[4];
#pragma unroll
    for (int i = 0; i < 4; ++i) {
        int chunk = i * 8 + wave;
        int mr = chunk * 2 + (lane >> 5);
        ksrc[i] = mr * 512 + (((lane & 31) * 16) ^ ((mr & 7) << 4));
        int c = chunk * 8 + (lane >> 3);
        vsrc[i] = c * (M_ * 2) + (((lane & 7) * 16) ^ ((c & 7) << 4));
    }

#pragma unroll
    for (int i = 0; i < 4; ++i)
        gload_lds16(Kg + ksrc[i], Kbase_l + (i * 8 + wave) * 1024);
#pragma unroll
    for (int i = 0; i < 4; ++i)
        gload_lds16(Vg + vsrc[i], Vbase_l + (i * 8 + wave) * 1024);

    f32x16 acc[8];
#pragma unroll
    for (int cb = 0; cb < 8; ++cb)
#pragma unroll
        for (int r = 0; r < 16; ++r) acc[cb][r] = 0.f;
    float m_run = -INFINITY, l_run = 0.f;

    asm volatile("s_waitcnt vmcnt(0)" ::: "memory");
    __builtin_amdgcn_s_barrier();
    asm volatile("" ::: "memory");

    for (int kt = 0; kt < NT; ++kt) {
        const int cur = kt & 1;
        if (kt + 1 < NT) {
            const char* Kn = Kg + (size_t)(kt + 1) * 32768;
            char* Kd = Kbase_l + (cur ^ 1) * 32768;
#pragma unroll
            for (int i = 0; i < 4; ++i)
                gload_lds16(Kn + ksrc[i], Kd + (i * 8 + wave) * 1024);
            const char* Vn = Vg + (size_t)(kt + 1) * 128;
            char* Vd = Vbase_l + (cur ^ 1) * 32768;
#pragma unroll
            for (int i = 0; i < 4; ++i)
                gload_lds16(Vn + vsrc[i], Vd + (i * 8 + wave) * 1024);
        }

        const char* Kc = Kbase_l + cur * 32768;
        const int mrow = mh * 32 + l31;
        const int msw = (mrow & 7) << 4;
        const int moff = mrow * 512;
        f32x16 s;
#pragma unroll
        for (int r = 0; r < 16; ++r) s[r] = 0.f;
        __builtin_amdgcn_s_setprio(1);
#pragma unroll
        for (int ks = 0; ks < 16; ++ks) {
            int cb2 = ks * 32 + hi * 16;
            bf16x8 a = *reinterpret_cast<const bf16x8*>(Kc + moff + (cb2 ^ msw));
            s = __builtin_amdgcn_mfma_f32_32x32x16_bf16(a, qf[ks], s, 0, 0, 0);
        }
        __builtin_amdgcn_s_setprio(0);

        // ---- online softmax over this m-half (scale already in q) ----
        // reduces use __shfl_xor: permlane-swap on IDENTICAL values coalesces
        // to a self-swap (round-8 bug) — keep the known-good crossbar path.
        float pv[16];
        float tm = -INFINITY;
#pragma unroll
        for (int r = 0; r < 16; ++r) {
            pv[r] = s[r];
            tm = fmaxf(tm, s[r]);
        }
        tm = fmaxf(tm, __shfl_xor(tm, 32));
        if (!__all(tm - m_run <= 8.0f)) {
            float m_new = fmaxf(m_run, tm);
            float corr = __expf(m_run - m_new);
#pragma unroll
            for (int cb = 0; cb < 8; ++cb)
#pragma unroll
                for (int r = 0; r < 16; ++r) acc[cb][r] *= corr;
            l_run *= corr;
            m_run = m_new;
        }
        float rs = 0.f;
#pragma unroll
        for (int i = 0; i < 16; ++i) { pv[i] = __expf(pv[i] - m_run); rs += pv[i]; }
        l_run += rs + __shfl_xor(rs, 32);

        // ---- build P B-frags: 4 permlane swaps (distinct operands -> safe) ----
        union PW { unsigned u[4]; bf16x8 v; };
        bf16x8 pfrag[2];
        {
            unsigned Ce0 = packbf(pv[0], pv[1]);
            unsigned Ce1 = packbf(pv[2], pv[3]);
            unsigned Ce2 = packbf(pv[4], pv[5]);
            unsigned Ce3 = packbf(pv[6], pv[7]);
            unsigned Co0 = packbf(pv[8], pv[9]);
            unsigned Co1 = packbf(pv[10], pv[11]);
            unsigned Co2 = packbf(pv[12], pv[13]);
            unsigned Co3 = packbf(pv[14], pv[15]);
            pl32swapu(Ce0, Ce2);   // Ce0=[lo|lo], Ce2=[hi|hi]
            pl32swapu(Ce1, Ce3);
            pl32swapu(Co0, Co2);
            pl32swapu(Co1, Co3);
            PW we, wo;
            we.u[0] = Ce0; we.u[1] = Ce1; we.u[2] = Ce2; we.u[3] = Ce3;
            wo.u[0] = Co0; wo.u[1] = Co1; wo.u[2] = Co2; wo.u[3] = Co3;
            pfrag[0] = we.v;
            pfrag[1] = wo.v;
        }

        const char* Vc = Vbase_l + cur * 32768;
        __builtin_amdgcn_s_setprio(1);
#pragma unroll
        for (int ks2 = 0; ks2 < 2; ++ks2) {
            int cb2 = (mh * 2 + ks2) * 32 + hi * 16;
#pragma unroll
            for (int cb = 0; cb < 8; ++cb) {
                int c = cb * 32 + l31;
                bf16x8 a = *reinterpret_cast<const bf16x8*>(Vc + c * 128 + (cb2 ^ ((c & 7) << 4)));
                acc[cb] = __builtin_amdgcn_mfma_f32_32x32x16_bf16(a, pfrag[ks2], acc[cb], 0, 0, 0);
            }
        }
        __builtin_amdgcn_s_setprio(0);

        asm volatile("s_waitcnt vmcnt(0)" ::: "memory");
        __builtin_amdgcn_s_barrier();
        asm volatile("" ::: "memory");
    }

    // ---- split-K merge between wave pairs (qg, 0) <-> (qg, 1) ----
    f32x2* mlb = (f32x2*)(smem + 131072);
    f32x2 myml; myml[0] = m_run; myml[1] = l_run;
    mlb[wave * 64 + lane] = myml;
    __syncthreads();
    f32x2 pml = mlb[(wave ^ 4) * 64 + lane];
    float m_star = fmaxf(m_run, pml[0]);
    float f_self = __expf(m_run - m_star);
    float f_peer = __expf(pml[0] - m_star);
    float l_tot = l_run * f_self + pml[1] * f_peer;
#pragma unroll
    for (int cb = 0; cb < 8; ++cb)
#pragma unroll
        for (int r = 0; r < 16; ++r) acc[cb][r] *= f_self;

    char* xbuf = smem;
    const int myoff = (qg * 2 + mh) * 16384;
    __syncthreads();
#pragma unroll
    for (int cbl = 0; cbl < 4; ++cbl)
#pragma unroll
        for (int q = 0; q < 4; ++q) {
            f32x4 chunk;
#pragma unroll
            for (int j = 0; j < 4; ++j) {
                float a_lo = acc[cbl][q * 4 + j];
                float a_hi = acc[4 + cbl][q * 4 + j];
                chunk[j] = mh ? a_lo : a_hi;
            }
            *reinterpret_cast<f32x4*>(xbuf + myoff + (cbl * 4 + q) * 1024 + lane * 16) = chunk;
        }
    __syncthreads();

    const int poff = (qg * 2 + (1 - mh)) * 16384;
    float gt = tanhf(gate[0]);
    float scale = gt / l_tot;
    const float* xp = x + (size_t)b * C_ * L_;
    float* op = out + (size_t)b * C_ * L_;
    int lcol = l0w + l31;
    const int cbase = mh * 4;
#pragma unroll
    for (int cbl = 0; cbl < 4; ++cbl) {
#pragma unroll
        for (int q = 0; q < 4; ++q) {
            f32x4 pc = *reinterpret_cast<const f32x4*>(xbuf + poff + (cbl * 4 + q) * 1024 + lane * 16);
#pragma unroll
            for (int j = 0; j < 4; ++j) {
                float a_lo = acc[cbl][q * 4 + j];
                float a_hi = acc[4 + cbl][q * 4 + j];
                float mine = mh ? a_hi : a_lo;
                int c = (cbase + cbl) * 32 + j + 8 * q + 4 * hi;
                size_t idx = (size_t)c * L_ + lcol;
                op[idx] = (mine + pc[j]) * scale + xp[idx];
            }
        }
    }
}

extern "C" void kernel_launch(void* const* d_in, const int* in_sizes, int n_in,
                              void* d_out, int out_size, void* d_ws, size_t ws_size,
                              hipStream_t stream) {
    const float* x    = (const float*)d_in[0];
    const float* Wq   = (const float*)d_in[1];
    const float* bq   = (const float*)d_in[2];
    const float* Wk   = (const float*)d_in[3];
    const float* bk   = (const float*)d_in[4];
    const float* Wv   = (const float*)d_in[5];
    const float* bv   = (const float*)d_in[6];
    const float* gate = (const float*)d_in[7];
    float* out = (float*)d_out;

    char* ws = (char*)d_ws;
    const size_t szKV = (size_t)B_ * M_ * C_ * 2;   // 8388608
    bf16_t* kbuf = (bf16_t*)(ws);
    bf16_t* vbuf = (bf16_t*)(ws + szKV);

    kv_proj_kernel<<<256, 256, 0, stream>>>(x, Wk, bk, Wv, bv, kbuf, vbuf);
    attn_kernel<<<256, 512, 0, stream>>>(Wq, bq, kbuf, vbuf, x, gate, out);
}